// Round 2
// baseline (102.278 us; speedup 1.0000x reference)
//
#include <hip/hip_runtime.h>
#include <hip/hip_bf16.h>

// BinarizedLinear: out[d,o] = (sum_i (u_w[d,o,i] < sigmoid(w[o,i])) * x[d,i])
//                             > bias[o] + (u_b[d,o]-0.5)*0.1
// D=128, OUT=1024, IN=1024. HBM-bound on the 512 MiB u_w stream.
// Output is bool -> marshalled as int32 (write 0/1 ints, NOT floats).

#define DD   128
#define OUTD 1024
#define IND  1024
#define D_PER_WAVE 8   // directions handled per wave (reuses sigmoid frags 8x)

__global__ __launch_bounds__(256) void BinarizedLinear_41360535061123_kernel(
    const int*   __restrict__ x,     // [D][IN]   (bool marshalled as int32)
    const float* __restrict__ w,     // [OUT][IN]
    const float* __restrict__ bias,  // [OUT]
    const float* __restrict__ u_w,   // [D][OUT][IN]
    const float* __restrict__ u_b,   // [D][OUT]
    int*         __restrict__ out)   // [D][OUT]  (bool as int32 0/1)
{
    const int gtid = blockIdx.x * blockDim.x + threadIdx.x;
    const int wave = gtid >> 6;
    const int lane = threadIdx.x & 63;

    // o fastest: consecutive waves stream contiguous u_w rows
    const int o  = wave & (OUTD - 1);
    const int dg = wave >> 10;          // 0 .. D/D_PER_WAVE-1
    const int d0 = dg * D_PER_WAVE;

    // Preload p = sigmoid(w[o, i]) fragment: lane l covers i = k*256 + l*4 .. +3
    const float4* w4 = reinterpret_cast<const float4*>(w + (size_t)o * IND);
    float4 p[4];
#pragma unroll
    for (int k = 0; k < 4; ++k) {
        float4 t = w4[k * 64 + lane];
        p[k].x = 1.0f / (1.0f + __expf(-t.x));
        p[k].y = 1.0f / (1.0f + __expf(-t.y));
        p[k].z = 1.0f / (1.0f + __expf(-t.z));
        p[k].w = 1.0f / (1.0f + __expf(-t.w));
    }

#pragma unroll
    for (int dd = 0; dd < D_PER_WAVE; ++dd) {
        const int d = d0 + dd;
        const float4* u4 = reinterpret_cast<const float4*>(
            u_w + ((size_t)d * OUTD + o) * IND);
        const int4* x4 = reinterpret_cast<const int4*>(x + (size_t)d * IND);

        int c = 0;
#pragma unroll
        for (int k = 0; k < 4; ++k) {
            float4 u  = u4[k * 64 + lane];
            int4   xb = x4[k * 64 + lane];
            c += (xb.x != 0) & (u.x < p[k].x);
            c += (xb.y != 0) & (u.y < p[k].y);
            c += (xb.z != 0) & (u.z < p[k].z);
            c += (xb.w != 0) & (u.w < p[k].w);
        }

        // wave-64 reduction
#pragma unroll
        for (int off = 32; off >= 1; off >>= 1)
            c += __shfl_down(c, off, 64);

        if (lane == 0) {
            const float thr = bias[o] + (u_b[(size_t)d * OUTD + o] - 0.5f) * 0.1f;
            out[(size_t)d * OUTD + o] = ((float)c > thr) ? 1 : 0;
        }
    }
}

extern "C" void kernel_launch(void* const* d_in, const int* in_sizes, int n_in,
                              void* d_out, int out_size, void* d_ws, size_t ws_size,
                              hipStream_t stream) {
    const int*   x    = (const int*)  d_in[0];
    const float* w    = (const float*)d_in[1];
    const float* bias = (const float*)d_in[2];
    const float* u_w  = (const float*)d_in[3];
    const float* u_b  = (const float*)d_in[4];
    int* out = (int*)d_out;

    // total waves = OUT * (D / D_PER_WAVE) = 1024 * 16 = 16384 ; 4 waves/block
    const int n_waves  = OUTD * (DD / D_PER_WAVE);
    const int n_blocks = n_waves / 4;   // 4096 blocks of 256 threads
    BinarizedLinear_41360535061123_kernel<<<n_blocks, 256, 0, stream>>>(
        x, w, bias, u_w, u_b, out);
}

// Round 4
// 92.268 us; speedup vs baseline: 1.1085x; 1.1085x over previous
//
#include <hip/hip_runtime.h>
#include <hip/hip_bf16.h>

// BinarizedLinear: out[d,o] = (sum_i (u_w[d,o,i] < sigmoid(w[o,i])) * x[d,i])
//                             > bias[o] + (u_b[d,o]-0.5)*0.1
// D=128, OUT=1024, IN=1024. HBM-bound on the 512 MiB u_w stream.
// Output is bool -> marshalled as int32 (write 0/1 ints).
//
// R4 = R3 with the nontemporal load done via a native clang vector type
// (__builtin_nontemporal_load rejects HIP_vector_type structs).

#define DD   128
#define OUTD 1024
#define IND  1024
#define D_PER_WAVE 8

typedef float floatx4 __attribute__((ext_vector_type(4)));

__global__ __launch_bounds__(256) void BinarizedLinear_41360535061123_kernel(
    const int*   __restrict__ x,     // [D][IN]   (bool as int32)
    const float* __restrict__ w,     // [OUT][IN]
    const float* __restrict__ bias,  // [OUT]
    const float* __restrict__ u_w,   // [D][OUT][IN]
    const float* __restrict__ u_b,   // [D][OUT]
    int*         __restrict__ out)   // [D][OUT]  (bool as int32 0/1)
{
    const int gtid = blockIdx.x * blockDim.x + threadIdx.x;
    const int wave = gtid >> 6;
    const int lane = threadIdx.x & 63;

    const int o  = wave & (OUTD - 1);   // o fastest: contiguous u_w rows
    const int dg = wave >> 10;
    const int d0 = dg * D_PER_WAVE;

    // Prefetch thresholds (L2-resident; overlap latency with sigmoid calc)
    float thr[D_PER_WAVE];
    {
        const float b = bias[o];
#pragma unroll
        for (int dd = 0; dd < D_PER_WAVE; ++dd)
            thr[dd] = b + (u_b[(size_t)(d0 + dd) * OUTD + o] - 0.5f) * 0.1f;
    }

    // p = sigmoid(w[o, i]) fragment: lane l covers i = k*256 + l*4 .. +3
    const float4* w4 = reinterpret_cast<const float4*>(w + (size_t)o * IND);
    float4 p[4];
#pragma unroll
    for (int k = 0; k < 4; ++k) {
        float4 t = w4[k * 64 + lane];
        p[k].x = 1.0f / (1.0f + __expf(-t.x));
        p[k].y = 1.0f / (1.0f + __expf(-t.y));
        p[k].z = 1.0f / (1.0f + __expf(-t.z));
        p[k].w = 1.0f / (1.0f + __expf(-t.w));
    }

    int c[D_PER_WAVE];
#pragma unroll
    for (int dd = 0; dd < D_PER_WAVE; ++dd) c[dd] = 0;

#pragma unroll
    for (int dd = 0; dd < D_PER_WAVE; ++dd) {
        const int d = d0 + dd;
        const floatx4* u4 = reinterpret_cast<const floatx4*>(
            u_w + ((size_t)d * OUTD + o) * IND);
        const int4* x4 = reinterpret_cast<const int4*>(x + (size_t)d * IND);

#pragma unroll
        for (int k = 0; k < 4; ++k) {
            floatx4 u  = __builtin_nontemporal_load(u4 + (k * 64 + lane));
            int4    xb = x4[k * 64 + lane];
            c[dd] += (xb.x != 0) & (u.x < p[k].x);
            c[dd] += (xb.y != 0) & (u.y < p[k].y);
            c[dd] += (xb.z != 0) & (u.z < p[k].z);
            c[dd] += (xb.w != 0) & (u.w < p[k].w);
        }
    }

    // Pack 2 counters per dword (each field <= 1024 after the 64-lane sum,
    // so 16-bit fields never carry), then one butterfly per packed dword.
    int r[D_PER_WAVE / 2];
#pragma unroll
    for (int k = 0; k < D_PER_WAVE / 2; ++k)
        r[k] = c[2 * k] | (c[2 * k + 1] << 16);

#pragma unroll
    for (int k = 0; k < D_PER_WAVE / 2; ++k) {
#pragma unroll
        for (int off = 32; off >= 1; off >>= 1)
            r[k] += __shfl_down(r[k], off, 64);
    }

    if (lane == 0) {
#pragma unroll
        for (int dd = 0; dd < D_PER_WAVE; ++dd) {
            const int cc = (r[dd >> 1] >> ((dd & 1) * 16)) & 0xffff;
            out[(size_t)(d0 + dd) * OUTD + o] = ((float)cc > thr[dd]) ? 1 : 0;
        }
    }
}

extern "C" void kernel_launch(void* const* d_in, const int* in_sizes, int n_in,
                              void* d_out, int out_size, void* d_ws, size_t ws_size,
                              hipStream_t stream) {
    const int*   x    = (const int*)  d_in[0];
    const float* w    = (const float*)d_in[1];
    const float* bias = (const float*)d_in[2];
    const float* u_w  = (const float*)d_in[3];
    const float* u_b  = (const float*)d_in[4];
    int* out = (int*)d_out;

    const int n_waves  = OUTD * (DD / D_PER_WAVE);   // 16384
    const int n_blocks = n_waves / 4;                // 4096 blocks x 256 thr
    BinarizedLinear_41360535061123_kernel<<<n_blocks, 256, 0, stream>>>(
        x, w, bias, u_w, u_b, out);
}